// Round 2
// baseline (850.710 us; speedup 1.0000x reference)
//
#include <hip/hip_runtime.h>
#include <cmath>

// B=2, L=2048, DIM=1024, NH=16, HD=64
typedef _Float16 half8 __attribute__((ext_vector_type(8)));
typedef _Float16 half4 __attribute__((ext_vector_type(4)));
typedef float f32x4 __attribute__((ext_vector_type(4)));

#define NEGBIG (-3.4028235e38f)

// async global->LDS, 16B per lane; LDS dest is wave-uniform base + lane*16
__device__ __forceinline__ void gload16(void* lds, const void* g) {
    __builtin_amdgcn_global_load_lds((const __attribute__((address_space(1))) void*)g,
                                     (__attribute__((address_space(3))) void*)lds, 16, 0, 0);
}

// ---------------- cast x: f32 -> f16 ----------------
__global__ void cast4_kernel(const float* __restrict__ in, _Float16* __restrict__ out, int n) {
    int i = (blockIdx.x * 256 + threadIdx.x) * 4;
    if (i < n) {
        float4 v = *(const float4*)&in[i];
        half4 o = { (_Float16)v.x, (_Float16)v.y, (_Float16)v.z, (_Float16)v.w };
        *(half4*)&out[i] = o;
    }
}

// ---------------- transpose+cast all 4 weights: W[k][n] f32 -> Wt[n][k] f16 ----------------
__global__ void transpose_cast_kernel(const float* __restrict__ W0, const float* __restrict__ W1,
                                      const float* __restrict__ W2, const float* __restrict__ W3,
                                      _Float16* __restrict__ T0, _Float16* __restrict__ T1,
                                      _Float16* __restrict__ T2, _Float16* __restrict__ T3) {
    const int z = blockIdx.z;
    const float* __restrict__ W = (z == 0) ? W0 : (z == 1) ? W1 : (z == 2) ? W2 : W3;
    _Float16* __restrict__ Wt   = (z == 0) ? T0 : (z == 1) ? T1 : (z == 2) ? T2 : T3;
    __shared__ float tile[32][33];
    int bx = blockIdx.x * 32;  // k base
    int by = blockIdx.y * 32;  // n base
    int tx = threadIdx.x & 31, ty = threadIdx.x >> 5;  // ty 0..7
    #pragma unroll
    for (int r = 0; r < 32; r += 8)
        tile[ty + r][tx] = W[(size_t)(bx + ty + r) * 1024 + by + tx];
    __syncthreads();
    #pragma unroll
    for (int r = 0; r < 32; r += 8)
        Wt[(size_t)(by + ty + r) * 1024 + bx + tx] = (_Float16)tile[tx][ty + r];
}

// ---------------- fused QKV GEMM (m97-style global_load_lds staging) ----------------
// z=0: Q -> Qh[b][h][l][d]; z=1: K -> Kh[b][h][l][d]; z=2: V -> VTh[b][h][d][l]
__global__ __launch_bounds__(256)
void gemm_qkv_kernel(const _Float16* __restrict__ X,
                     const _Float16* __restrict__ WqT, const _Float16* __restrict__ WkT,
                     const _Float16* __restrict__ WvT,
                     _Float16* __restrict__ Qh, _Float16* __restrict__ Kh, _Float16* __restrict__ VTh)
{
    const int z = blockIdx.z;
    const _Float16* __restrict__ Bt = (z == 0) ? WqT : (z == 1) ? WkT : WvT;
    _Float16* __restrict__ out      = (z == 0) ? Qh  : (z == 1) ? Kh  : VTh;

    __shared__ __align__(16) _Float16 As[128][32];
    __shared__ __align__(16) _Float16 Bs[128][32];

    const int tid = threadIdx.x;
    const int bm = blockIdx.x * 128;
    const int bn = blockIdx.y * 128;
    const int wave = tid >> 6, lane = tid & 63;
    const int wm = (wave >> 1) * 64, wn = (wave & 1) * 64;
    const int quad = lane >> 4, l16 = lane & 15;

    // staging: wave w owns rows [w*32, w*32+32) of each tile, 2 chunks of 16 rows
    const int srow = wave * 32 + (lane >> 2);      // + 16 for chunk 1
    const int scol = (lane & 3) * 8;
    const _Float16* gA = &X [(size_t)(bm + srow) * 1024 + scol];
    const _Float16* gB = &Bt[(size_t)(bn + srow) * 1024 + scol];

    f32x4 acc[4][4] = {};

    for (int k0 = 0; k0 < 1024; k0 += 32) {
        gload16(&As[wave * 32][0],      gA + k0);
        gload16(&As[wave * 32 + 16][0], gA + 16 * 1024 + k0);
        gload16(&Bs[wave * 32][0],      gB + k0);
        gload16(&Bs[wave * 32 + 16][0], gB + 16 * 1024 + k0);
        __syncthreads();

        half8 af[4], bf[4];
        #pragma unroll
        for (int mt = 0; mt < 4; ++mt) af[mt] = *(const half8*)&As[wm + mt*16 + l16][quad * 8];
        #pragma unroll
        for (int nt = 0; nt < 4; ++nt) bf[nt] = *(const half8*)&Bs[wn + nt*16 + l16][quad * 8];
        if (z == 2) {
            #pragma unroll
            for (int mt = 0; mt < 4; ++mt)
                #pragma unroll
                for (int nt = 0; nt < 4; ++nt)
                    acc[mt][nt] = __builtin_amdgcn_mfma_f32_16x16x32_f16(bf[nt], af[mt], acc[mt][nt], 0, 0, 0);
        } else {
            #pragma unroll
            for (int mt = 0; mt < 4; ++mt)
                #pragma unroll
                for (int nt = 0; nt < 4; ++nt)
                    acc[mt][nt] = __builtin_amdgcn_mfma_f32_16x16x32_f16(af[mt], bf[nt], acc[mt][nt], 0, 0, 0);
        }
        __syncthreads();
    }

    if (z < 2) {
        // C/D layout: col=lane&15 (n), row=quad*4+r (m)
        #pragma unroll
        for (int mt = 0; mt < 4; ++mt) {
            #pragma unroll
            for (int nt = 0; nt < 4; ++nt) {
                #pragma unroll
                for (int r = 0; r < 4; ++r) {
                    int m = bm + wm + mt * 16 + quad * 4 + r;   // b*L+l
                    int n = bn + wn + nt * 16 + l16;            // h*64+d
                    _Float16 hv = (_Float16)acc[mt][nt][r];
                    int bb = m >> 11, ll = m & 2047, hh = n >> 6, dd = n & 63;
                    out[(((size_t)(bb * 16 + hh)) * 2048 + ll) * 64 + dd] = hv;
                }
            }
        }
    } else {
        // swapped: col=lane&15 -> m (X row), row=quad*4+r -> n (h*64+d); contiguous in l
        #pragma unroll
        for (int mt = 0; mt < 4; ++mt) {
            #pragma unroll
            for (int nt = 0; nt < 4; ++nt) {
                #pragma unroll
                for (int r = 0; r < 4; ++r) {
                    int n = bn + wn + nt * 16 + quad * 4 + r;   // h*64+d
                    int m = bm + wm + mt * 16 + l16;            // b*2048+l
                    _Float16 hv = (_Float16)acc[mt][nt][r];
                    int bb = m >> 11, ll = m & 2047, hh = n >> 6, dd = n & 63;
                    out[(((size_t)(bb * 16 + hh)) * 64 + dd) * 2048 + ll] = hv;
                }
            }
        }
    }
}

// ---------------- flash attention, fully-swapped layout (lane-local q rows) ----------------
__global__ __launch_bounds__(256)
void flash_attn_kernel(const _Float16* __restrict__ Qh, const _Float16* __restrict__ Kh,
                       const _Float16* __restrict__ VTh, const float* __restrict__ bias,
                       const int* __restrict__ mask, _Float16* __restrict__ AO)
{
    const int qt = blockIdx.x, h = blockIdx.y, b = blockIdx.z;
    const int tid = threadIdx.x, wave = tid >> 6, lane = tid & 63;
    const int quad = lane >> 4, l16 = lane & 15;

    __shared__ _Float16 Kt[64][72];      // [j][d]
    __shared__ _Float16 Vt[64][72];      // [d][j]
    __shared__ _Float16 Pw[4][16][72];   // per-wave P: [q][j]

    const size_t head = (size_t)(b * 16 + h) * 2048 * 64;
    const int i_base = qt * 64 + wave * 16;
    const int qrow = i_base + l16;                        // this lane's q row
    const float* __restrict__ bias_row = bias + ((size_t)((b * 16 + h) * 2048 + qrow)) * 2048;
    const int* __restrict__ mask_base = mask + b * 2048;

    // Q fragment (B-operand: n=lane&15=q, k=quad*8+j)
    half8 qf0 = *(const half8*)&Qh[head + (size_t)qrow * 64 + quad * 8];
    half8 qf1 = *(const half8*)&Qh[head + (size_t)qrow * 64 + 32 + quad * 8];

    float m_r = -INFINITY, l_r = 0.f;
    f32x4 o[4] = {};   // o[nt][r]: d = nt*16+quad*4+r, q = l16

    // K/V staging indices
    const int kv_row = tid >> 3;         // +c*32 -> 0..63
    const int kv_dc  = (tid & 7) * 8;    // 0..56

    half8 kreg[2], vreg[2];
    f32x4 breg[4];
    int4  mreg[4];

    auto prefetchKV = [&](int j0) {
        #pragma unroll
        for (int c = 0; c < 2; ++c) {
            int row = kv_row + c * 32;
            kreg[c] = *(const half8*)&Kh [head + (size_t)(j0 + row) * 64 + kv_dc];
            vreg[c] = *(const half8*)&VTh[head + (size_t)row * 2048 + j0 + kv_dc];
        }
    };
    auto prefetchB = [&](int j0) {
        #pragma unroll
        for (int jt = 0; jt < 4; ++jt) {
            breg[jt] = *(const f32x4*)&bias_row [j0 + jt * 16 + quad * 4];
            mreg[jt] = *(const int4*) &mask_base[j0 + jt * 16 + quad * 4];
        }
    };

    prefetchKV(0);
    prefetchB(0);

    for (int j0 = 0; j0 < 2048; j0 += 64) {
        #pragma unroll
        for (int c = 0; c < 2; ++c) {
            int row = kv_row + c * 32;
            *(half8*)&Kt[row][kv_dc] = kreg[c];
            *(half8*)&Vt[row][kv_dc] = vreg[c];
        }
        __syncthreads();
        if (j0 + 64 < 2048) prefetchKV(j0 + 64);

        // QK^T swapped: s = K·Q^T -> S^T[j][q]; lane holds q=l16, j=jt*16+quad*4+r
        float sreg[16];
        #pragma unroll
        for (int jt = 0; jt < 4; ++jt) {
            half8 kf0 = *(const half8*)&Kt[jt * 16 + l16][quad * 8];
            half8 kf1 = *(const half8*)&Kt[jt * 16 + l16][32 + quad * 8];
            f32x4 s = {};
            __builtin_amdgcn_s_setprio(1);
            s = __builtin_amdgcn_mfma_f32_16x16x32_f16(kf0, qf0, s, 0, 0, 0);
            s = __builtin_amdgcn_mfma_f32_16x16x32_f16(kf1, qf1, s, 0, 0, 0);
            __builtin_amdgcn_s_setprio(0);
            sreg[jt*4+0] = mreg[jt].x ? (s[0] + breg[jt][0]) : NEGBIG;
            sreg[jt*4+1] = mreg[jt].y ? (s[1] + breg[jt][1]) : NEGBIG;
            sreg[jt*4+2] = mreg[jt].z ? (s[2] + breg[jt][2]) : NEGBIG;
            sreg[jt*4+3] = mreg[jt].w ? (s[3] + breg[jt][3]) : NEGBIG;
        }
        if (j0 + 64 < 2048) prefetchB(j0 + 64);

        // lane-local softmax over this lane's 16 j-values, then 2-shuffle cross-quad reduce
        float mx = sreg[0];
        #pragma unroll
        for (int i = 1; i < 16; ++i) mx = fmaxf(mx, sreg[i]);
        mx = fmaxf(mx, __shfl_xor(mx, 16));
        mx = fmaxf(mx, __shfl_xor(mx, 32));
        float mnew = fmaxf(m_r, mx);
        float alpha = __expf(m_r - mnew);
        m_r = mnew;

        float p[16], ps = 0.f;
        #pragma unroll
        for (int i = 0; i < 16; ++i) { p[i] = __expf(sreg[i] - mnew); ps += p[i]; }
        #pragma unroll
        for (int jt = 0; jt < 4; ++jt) {
            half4 pk = { (_Float16)p[jt*4], (_Float16)p[jt*4+1],
                         (_Float16)p[jt*4+2], (_Float16)p[jt*4+3] };
            *(half4*)&Pw[wave][l16][jt * 16 + quad * 4] = pk;
        }
        ps += __shfl_xor(ps, 16);
        ps += __shfl_xor(ps, 32);
        l_r = l_r * alpha + ps;
        #pragma unroll
        for (int nt = 0; nt < 4; ++nt) {
            o[nt][0] *= alpha; o[nt][1] *= alpha; o[nt][2] *= alpha; o[nt][3] *= alpha;
        }

        // PV swapped: o = V^T·P^T -> O^T[d][q]; P as B-operand (n=l16=q, k=quad*8+j)
        half8 pf0 = *(const half8*)&Pw[wave][l16][quad * 8];
        half8 pf1 = *(const half8*)&Pw[wave][l16][32 + quad * 8];
        #pragma unroll
        for (int nt = 0; nt < 4; ++nt) {
            half8 vf0 = *(const half8*)&Vt[nt * 16 + l16][quad * 8];
            half8 vf1 = *(const half8*)&Vt[nt * 16 + l16][32 + quad * 8];
            __builtin_amdgcn_s_setprio(1);
            o[nt] = __builtin_amdgcn_mfma_f32_16x16x32_f16(vf0, pf0, o[nt], 0, 0, 0);
            o[nt] = __builtin_amdgcn_mfma_f32_16x16x32_f16(vf1, pf1, o[nt], 0, 0, 0);
            __builtin_amdgcn_s_setprio(0);
        }
        __syncthreads();
    }

    const float inv = 1.0f / l_r;
    #pragma unroll
    for (int nt = 0; nt < 4; ++nt) {
        half4 ov = { (_Float16)(o[nt][0] * inv), (_Float16)(o[nt][1] * inv),
                     (_Float16)(o[nt][2] * inv), (_Float16)(o[nt][3] * inv) };
        *(half4*)&AO[(size_t)(b * 2048 + qrow) * 1024 + h * 64 + nt * 16 + quad * 4] = ov;
    }
}

// ---------------- output projection (m97-style staging): AO @ woT -> f32 out ----------------
__global__ __launch_bounds__(256)
void gemm_out_kernel(const _Float16* __restrict__ A, const _Float16* __restrict__ Bt,
                     float* __restrict__ C)
{
    __shared__ __align__(16) _Float16 As[128][32];
    __shared__ __align__(16) _Float16 Bs[128][32];

    const int tid = threadIdx.x;
    const int bm = blockIdx.x * 128;
    const int bn = blockIdx.y * 128;
    const int wave = tid >> 6, lane = tid & 63;
    const int wm = (wave >> 1) * 64, wn = (wave & 1) * 64;
    const int quad = lane >> 4, l16 = lane & 15;

    const int srow = wave * 32 + (lane >> 2);
    const int scol = (lane & 3) * 8;
    const _Float16* gA = &A [(size_t)(bm + srow) * 1024 + scol];
    const _Float16* gB = &Bt[(size_t)(bn + srow) * 1024 + scol];

    f32x4 acc[4][4] = {};

    for (int k0 = 0; k0 < 1024; k0 += 32) {
        gload16(&As[wave * 32][0],      gA + k0);
        gload16(&As[wave * 32 + 16][0], gA + 16 * 1024 + k0);
        gload16(&Bs[wave * 32][0],      gB + k0);
        gload16(&Bs[wave * 32 + 16][0], gB + 16 * 1024 + k0);
        __syncthreads();

        half8 af[4], bf[4];
        #pragma unroll
        for (int mt = 0; mt < 4; ++mt) af[mt] = *(const half8*)&As[wm + mt*16 + l16][quad * 8];
        #pragma unroll
        for (int nt = 0; nt < 4; ++nt) bf[nt] = *(const half8*)&Bs[wn + nt*16 + l16][quad * 8];
        #pragma unroll
        for (int mt = 0; mt < 4; ++mt)
            #pragma unroll
            for (int nt = 0; nt < 4; ++nt)
                acc[mt][nt] = __builtin_amdgcn_mfma_f32_16x16x32_f16(af[mt], bf[nt], acc[mt][nt], 0, 0, 0);
        __syncthreads();
    }

    #pragma unroll
    for (int mt = 0; mt < 4; ++mt)
        #pragma unroll
        for (int nt = 0; nt < 4; ++nt)
            #pragma unroll
            for (int r = 0; r < 4; ++r) {
                int m = bm + wm + mt * 16 + quad * 4 + r;
                int n = bn + wn + nt * 16 + l16;
                C[(size_t)m * 1024 + n] = acc[mt][nt][r];
            }
}

extern "C" void kernel_launch(void* const* d_in, const int* in_sizes, int n_in,
                              void* d_out, int out_size, void* d_ws, size_t ws_size,
                              hipStream_t stream)
{
    const float* x    = (const float*)d_in[0];
    const float* bias = (const float*)d_in[1];
    const int*   mask = (const int*)d_in[2];
    const float* wq   = (const float*)d_in[3];
    const float* wk   = (const float*)d_in[4];
    const float* wv   = (const float*)d_in[5];
    const float* wo   = (const float*)d_in[6];
    float* out = (float*)d_out;

    char* ws = (char*)d_ws;
    const size_t MB = 1024 * 1024;
    _Float16* x_h = (_Float16*)(ws + 0);        // 8 MB; reused as AO after QKV GEMMs
    _Float16* AO  = x_h;
    _Float16* wqT = (_Float16*)(ws + 8 * MB);
    _Float16* wkT = (_Float16*)(ws + 10 * MB);
    _Float16* wvT = (_Float16*)(ws + 12 * MB);
    _Float16* woT = (_Float16*)(ws + 14 * MB);
    _Float16* Qh  = (_Float16*)(ws + 16 * MB);  // [b][h][l][d]
    _Float16* Kh  = (_Float16*)(ws + 24 * MB);  // [b][h][l][d]
    _Float16* VTh = (_Float16*)(ws + 32 * MB);  // [b][h][d][l] (ends at 40 MB)

    cast4_kernel<<<4096, 256, 0, stream>>>(x, x_h, 4096 * 1024);
    transpose_cast_kernel<<<dim3(32, 32, 4), 256, 0, stream>>>(wq, wk, wv, wo, wqT, wkT, wvT, woT);

    gemm_qkv_kernel<<<dim3(32, 8, 3), 256, 0, stream>>>(x_h, wqT, wkT, wvT, Qh, Kh, VTh);
    flash_attn_kernel<<<dim3(32, 16, 2), 256, 0, stream>>>(Qh, Kh, VTh, bias, mask, AO);
    gemm_out_kernel<<<dim3(32, 8), 256, 0, stream>>>(AO, woT, out);
}